// Round 7
// baseline (6032.104 us; speedup 1.0000x reference)
//
#include <hip/hip_runtime.h>

// ---------------------------------------------------------------------------
// TGCN2 forward, MI355X gfx950. R17 = R16 + one-step-deep REGISTER PIPELINE
// for all LLC ring loads.
// R16 post-mortem: group-batched sync gave -22%; remaining 7us/step is
// exposed LLC load latency (L1/L0: 12 gcur loads covered by only ~0.2us of
// MFMA; helpers: 8 h0seq loads/step). R17:
//   - L-blocks: gA/gB (GI for mtg0/mtg1) loaded during step t-1 after old
//     values consumed -> full-step latency cover. Same-group prefetch always
//     safe; group-boundary prefetch gated on a speculative stamp read
//     (evaluated under mtg0's MFMA phase), blocking fallback otherwise.
//   - Helpers: 4-step group processed with A0/A1 ping-pong prefetch (step
//     k+1 loads issued before step k's MFMAs); only group-boundary blocking.
//   - mtg bodies as static macro instances + sched_barrier(0) between them
//     (no dynamic reg-array indexing; no cross-body pressure interleave).
// Sync structure unchanged from R16 (group stamps, SLACK, drains 1/group).
// Structure validated R13..R16, absmax 2.44e-4. TGCN on side stream (R7).
// ---------------------------------------------------------------------------

typedef unsigned short u16;
typedef unsigned long long u64;
typedef short s8v __attribute__((ext_vector_type(8)));
typedef _Float16 h8v __attribute__((ext_vector_type(8)));
typedef float f4v __attribute__((ext_vector_type(4)));

#define NBATCH 64
#define NNODE  512
#define DCIN   128
#define DHID   256
#define NEDGE  8192
#define RSLOT  64
#define SLACK  56
#define NGRP   (NNODE / 4)

#define AT_LD(p)   __hip_atomic_load((p), __ATOMIC_RELAXED, __HIP_MEMORY_SCOPE_AGENT)
#define AT_ST(p,v) __hip_atomic_store((p), (v), __ATOMIC_RELAXED, __HIP_MEMORY_SCOPE_AGENT)

__device__ __forceinline__ u16 f2b(float f) {
    union { float f; unsigned int i; } v; v.f = f;
    unsigned int x = v.i;
    return (u16)((x + 0x7FFFu + ((x >> 16) & 1u)) >> 16);   // RNE (TGCN path)
}
__device__ __forceinline__ float sigm(float x)  { return 1.0f / (1.0f + __expf(-x)); }
__device__ __forceinline__ float tanh_(float x) { return 1.0f - 2.0f / (1.0f + __expf(2.0f * x)); }
__device__ __forceinline__ f4v mfma16(s8v a, s8v b, f4v c) {
    return __builtin_amdgcn_mfma_f32_16x16x32_bf16(a, b, c, 0, 0, 0);
}
__device__ __forceinline__ f4v mfma16h(h8v a, h8v b, f4v c) {
    return __builtin_amdgcn_mfma_f32_16x16x32_f16(a, b, c, 0, 0, 0);
}
__device__ __forceinline__ f4v ld_ring_f4(const u64* p) {
    union { u64 d[2]; f4v v; } u;
    u.d[0] = AT_LD(p); u.d[1] = AT_LD(p + 1);
    return u.v;
}
__device__ __forceinline__ void st_ring_f4(u64* p, f4v v) {
    union { f4v v; u64 d[2]; } u; u.v = v;
    AT_ST(p, u.d[0]); AT_ST(p + 1, u.d[1]);
}
__device__ __forceinline__ h8v ld_ring_h8(const u64* p) {
    union { u64 d[2]; h8v v; } u;
    u.d[0] = AT_LD(p); u.d[1] = AT_LD(p + 1);
    return u.v;
}
__device__ __forceinline__ void st_ring_h8(u64* p, h8v v) {
    union { h8v v; u64 d[2]; } u; u.v = v;
    AT_ST(p, u.d[0]); AT_ST(p + 1, u.d[1]);
}
__device__ __forceinline__ u16 f2h_bits(float f) {
    _Float16 h = (_Float16)f;
    return __builtin_bit_cast(u16, h);
}

// --------------------------- graph preprocessing ---------------------------
__global__ void init_kernel(float* deg, int* counts, int* syncb) {
    int i = blockIdx.x * blockDim.x + threadIdx.x;
    if (i < NNODE) { deg[i] = 2.0f; counts[i] = 1; }
    if (i < 4096) syncb[i] = -1;   // prog/progH/stamps: must be < 0
}

__global__ void edge_deg_kernel(const int* __restrict__ ei, const float* __restrict__ ew,
                                float* deg, int* counts) {
    int e = blockIdx.x * blockDim.x + threadIdx.x;
    if (e < NEDGE) {
        int t = ei[NEDGE + e];
        atomicAdd(&deg[t], ew[e]);
        atomicAdd(&counts[t], 1);
    }
}

__global__ void scan_kernel(const float* __restrict__ deg, const int* __restrict__ counts,
                            float* __restrict__ dinv, int* __restrict__ rowptr,
                            int* __restrict__ cursor, int* __restrict__ col,
                            float* __restrict__ val) {
    __shared__ int sc[NNODE];
    int i = threadIdx.x;
    float d = deg[i];
    float di = (d > 0.0f) ? (1.0f / sqrtf(d)) : 0.0f;
    dinv[i] = di;
    int cnt = counts[i];
    sc[i] = cnt;
    __syncthreads();
    for (int ofs = 1; ofs < NNODE; ofs <<= 1) {
        int add = (i >= ofs) ? sc[i - ofs] : 0;
        __syncthreads();
        sc[i] += add;
        __syncthreads();
    }
    int ex = sc[i] - cnt;
    rowptr[i] = ex;
    if (i == NNODE - 1) rowptr[NNODE] = sc[NNODE - 1];
    col[ex] = i;
    val[ex] = di * 2.0f * di;
    cursor[i] = ex + 1;
}

__global__ void fill_kernel(const int* __restrict__ ei, const float* __restrict__ ew,
                            const float* __restrict__ dinv, int* cursor,
                            int* __restrict__ col, float* __restrict__ val) {
    int e = blockIdx.x * blockDim.x + threadIdx.x;
    if (e < NEDGE) {
        int s = ei[e], t = ei[NEDGE + e];
        int p = atomicAdd(&cursor[t], 1);
        col[p] = s;
        val[p] = dinv[s] * ew[e] * dinv[t];
    }
}

// Wf[2j+g][k] = sum_m Wg[k][m]*Lg_top[m][j]; bfold[2j+g] = bg@Lg_top[:,j]+lgb[j]
__global__ void fold_kernel(const float* __restrict__ Wz, const float* __restrict__ lzW,
                            const float* __restrict__ bz, const float* __restrict__ lzb,
                            const float* __restrict__ Wh, const float* __restrict__ lhW,
                            const float* __restrict__ bh, const float* __restrict__ lhb,
                            u16* __restrict__ Wf, float* __restrict__ bfold) {
    int nidx = blockIdx.x;
    int g = nidx & 1, j = nidx >> 1;
    int k = threadIdx.x;
    const float* W = g ? Wh : Wz;
    const float* L = g ? lhW : lzW;
    float acc = 0.0f;
    for (int m = 0; m < DHID; ++m)
        acc += W[k * DHID + m] * L[m * DHID + j];
    Wf[nidx * DCIN + k] = f2b(acc);
    if (k == 0) {
        const float* bg = g ? bh : bz;
        const float* lb = g ? lhb : lzb;
        float ab = 0.0f;
        for (int m = 0; m < DHID; ++m) ab += bg[m] * L[m * DHID + j];
        bfold[nidx] = ab + lb[j];
    }
}

// ----------------------------- weight repacks (f16) ------------------------
__global__ void pack_whh_kernel(const float* __restrict__ Whh0,
                                const float* __restrict__ Whh1, u16* __restrict__ dst) {
    int id = blockIdx.x * 256 + threadIdx.x;
    if (id >= 2 * 8 * 8 * 6 * 64) return;
    int l = id & 63; int r = id >> 6;
    int nt = r % 6; r /= 6;
    int kc = r % 8; r /= 8;
    int wv = r % 8; r /= 8;
    const float* src = r ? Whh1 : Whh0;
    int ch = (nt >> 1) * 256 + wv * 32 + (nt & 1) * 16 + (l & 15);
    int k0 = kc * 32 + (l >> 4) * 8;
    u16* d = dst + (size_t)id * 8;
    #pragma unroll
    for (int e = 0; e < 8; ++e) d[e] = f2h_bits(src[(size_t)ch * 256 + k0 + e]);
}

__global__ void pack_wih_kernel(const float* __restrict__ W, int K, int KC,
                                u16* __restrict__ dst) {
    int id = blockIdx.x * 256 + threadIdx.x;
    if (id >= 8 * KC * 6 * 64) return;
    int l = id & 63; int r = id >> 6;
    int nt = r % 6; r /= 6;
    int kc = r % KC; r /= KC;
    int pb = r;
    int ch = (pb * 6 + nt) * 16 + (l & 15);
    int k0 = kc * 32 + (l >> 4) * 8;
    u16* d = dst + (size_t)id * 8;
    #pragma unroll
    for (int e = 0; e < 8; ++e) d[e] = f2h_bits(W[(size_t)ch * K + k0 + e]);
}

// --------------- fused TGCN: aggregate + GEMM + cell + l1-dot --------------
__global__ __launch_bounds__(256)
void tgcn_kernel(const float* __restrict__ x, const int* __restrict__ rowptr,
                 const int* __restrict__ col, const float* __restrict__ val,
                 const u16* __restrict__ Wf, const float* __restrict__ bfold,
                 const float* __restrict__ l1W, float* __restrict__ hdot) {
    __shared__ u16 As[64][136];
    const int tid = threadIdx.x;
    const int bx = blockIdx.x;
    const int b = bx >> 3;
    const int n0 = (bx & 7) * 64;
    {
        const int c = tid & 127;
        const int half = tid >> 7;
        for (int it = 0; it < 32; ++it) {
            int r = it * 2 + half;
            int n = n0 + r;
            int s = rowptr[n], e = rowptr[n + 1];
            float acc = 0.0f;
            for (int i = s; i < e; ++i)
                acc += val[i] * x[((size_t)b * NNODE + col[i]) * DCIN + c];
            As[r][c] = f2b(acc);
        }
    }
    __syncthreads();
    const int w = tid >> 6, l = tid & 63;
    const int ncol = l & 15, q = l >> 4, ko = q * 8;
    s8v af[4];
    #pragma unroll
    for (int kc = 0; kc < 4; ++kc)
        af[kc] = *(const s8v*)(&As[w * 16 + ncol][kc * 32 + ko]);
    float partial[4] = {0.f, 0.f, 0.f, 0.f};
    for (int nc = 0; nc < 32; ++nc) {
        int n = nc * 16 + ncol;
        const u16* brow = Wf + (size_t)n * DCIN + ko;
        f4v acc = {0.f, 0.f, 0.f, 0.f};
        #pragma unroll
        for (int kc = 0; kc < 4; ++kc)
            acc = mfma16(af[kc], *(const s8v*)(brow + kc * 32), acc);
        float bias = bfold[n];
        float l1w = l1W[n >> 1];
        #pragma unroll
        for (int rr = 0; rr < 4; ++rr) {
            float v = acc[rr] + bias;
            float o = __shfl_xor(v, 1);
            float zpre = (ncol & 1) ? o : v;
            float hpre = (ncol & 1) ? v : o;
            float hn = (1.0f - sigm(zpre)) * tanh_(hpre);
            hn = hn > 0.0f ? hn : 0.0f;
            if (!(ncol & 1)) partial[rr] += hn * l1w;
        }
    }
    #pragma unroll
    for (int rr = 0; rr < 4; ++rr) {
        float p = partial[rr];
        p += __shfl_xor(p, 1); p += __shfl_xor(p, 2);
        p += __shfl_xor(p, 4); p += __shfl_xor(p, 8);
        if (ncol == 0)
            hdot[bx * 64 + w * 16 + q * 4 + rr] = p;
    }
}

// --------------------- GRU: persistent 20-block pipeline -------------------
// bid 0=L0a, 1=L0b, 2=L1a, 3=L1b; bid 4..11 feeders; bid 12..19 helpers.
// syncb: [0..3] progL (steps), [64..127] progH[pb*8+wv] (groups),
//        [128..383] stH[16][16] (groups), [384..511] stG0[16][8],
//        [512..639] stG1[16][8].  Init -1.

// helper pipelined step: prefetch step K+1's A-frags, then MFMA+store step K
#define HSTEP(K, ACUR, ANXT, PF) { \
    const int t_ = gr * 4 + (K); \
    const int s_ = t_ & (RSLOT - 1); \
    if (PF) { \
        const int sn_ = (t_ + 1) & (RSLOT - 1); \
        _Pragma("unroll") \
        for (int kc = 0; kc < 8; ++kc) \
            ANXT[kc] = ld_ring_h8((const u64*)(h0c + \
                (((size_t)(sn_ * 8 + kc) * 4 + mt) * 64 + l) * 16)); \
    } \
    _Pragma("unroll") \
    for (int j = 0; j < 3; ++j) { \
        f4v acc = {biasp[j], biasp[j], biasp[j], biasp[j]}; \
        _Pragma("unroll") \
        for (int kc = 0; kc < 8; ++kc) acc = mfma16h(ACUR[kc], wrp[kc][j], acc); \
        int NT = pb * 6 + gg * 3 + j; \
        st_ring_f4((u64*)((char*)gid + \
            (((size_t)s_ * 48 + NT) * 4 + mt) * 1024 + l * 16), acc); \
    } \
    __builtin_amdgcn_sched_barrier(0); \
}

// L-block per-M-tile body. GREG = this tile's GI regs (consumed, then
// refilled for t+1 when pfNext).
#define L_MTG(MTG, GREG) { \
    const int mt = half * 2 + (MTG); \
    f4v acc[6]; \
    _Pragma("unroll") \
    for (int nt = 0; nt < 6; ++nt) acc[nt] = (f4v){0.f, 0.f, 0.f, 0.f}; \
    if (t > 0) { \
        const int b = (MTG) * 16 + (l & 15); \
        _Pragma("unroll") \
        for (int kc = 0; kc < 6; ++kc) { \
            int boff = (b << 9) + ((((kc << 6) + ((l >> 4) << 4)) ^ ((b & 7) << 4))); \
            h8v A = *(const h8v*)(hst + rb * 16384 + boff); \
            _Pragma("unroll") \
            for (int nt = 0; nt < 6; ++nt) \
                acc[nt] = mfma16h(A, wr[kc][nt], acc[nt]); \
        } \
        _Pragma("unroll") \
        for (int kcx = 0; kcx < 2; ++kcx) { \
            int kc = 6 + kcx; \
            int boff = (b << 9) + ((((kc << 6) + ((l >> 4) << 4)) ^ ((b & 7) << 4))); \
            h8v A = *(const h8v*)(hst + rb * 16384 + boff); \
            _Pragma("unroll") \
            for (int nt = 0; nt < 6; ++nt) { \
                h8v wl = *(const h8v*)&whhlds[kcx][wv][nt][l * 8]; \
                acc[nt] = mfma16h(A, wl, acc[nt]); \
            } \
        } \
    } \
    if ((MTG) == 0) \
        pfNext = (t + 1 < NNODE) && (gph < 3 || __all(stvn >= g + 1)); \
    float pd01[4]; \
    _Pragma("unroll") \
    for (int rr = 0; rr < 4; ++rr) { \
        int b2 = (MTG) * 16 + (l >> 4) * 4 + rr; \
        float pdv = 0.f; \
        _Pragma("unroll") \
        for (int h = 0; h < 2; ++h) { \
            float rv = sigm(acc[h][rr] + GREG[h][rr]); \
            float zv = sigm(acc[2 + h][rr] + GREG[2 + h][rr]); \
            float nv = tanh_(GREG[4 + h][rr] + rv * (acc[4 + h][rr] + bhn[h])); \
            int ch2 = (wv * 32 + h * 16 + (l & 15)) * 2; \
            int boff = (b2 << 9) + (ch2 ^ ((b2 & 7) << 4)); \
            float ho = 0.f; \
            if (t > 0) { \
                u16 hb_ = *(const u16*)(hst + rb * 16384 + boff); \
                ho = (float)__builtin_bit_cast(_Float16, hb_); \
            } \
            float hn = nv + zv * (ho - nv); \
            *(u16*)(hst + wb * 16384 + boff) = f2h_bits(hn); \
            pdv += hn * l2v[h]; \
        } \
        pd01[rr] = pdv; \
    } \
    if (pfNext) { \
        const int s1 = (t + 1) & (RSLOT - 1); \
        _Pragma("unroll") \
        for (int j = 0; j < 6; ++j) { \
            int NT = (j >> 1) * 16 + 2 * wv + (j & 1); \
            GREG[j] = ld_ring_f4((const u64*)(gis + \
                (((size_t)s1 * 48 + NT) * 4 + mt) * 1024 + l * 16)); \
        } \
    } \
    if (!isL1) { \
        asm volatile("s_waitcnt lgkmcnt(0)" ::: "memory"); \
        int b = (MTG) * 16 + (l & 15); \
        int boff = (b << 9) + ((((wv << 6) + ((l >> 4) << 4)) ^ ((b & 7) << 4))); \
        h8v hv = *(const h8v*)(hst + wb * 16384 + boff); \
        st_ring_h8((u64*)(h0c + (((size_t)(s * 8 + wv) * 4 + mt) * 64 + l) * 16), hv); \
    } else { \
        _Pragma("unroll") \
        for (int rr = 0; rr < 4; ++rr) { \
            float v = pd01[rr]; \
            v += __shfl_xor(v, 1); v += __shfl_xor(v, 2); \
            v += __shfl_xor(v, 4); v += __shfl_xor(v, 8); \
            pd01[rr] = v; \
        } \
        if ((l & 15) == 0) { \
            f4v pv = {pd01[0], pd01[1], pd01[2], pd01[3]}; \
            *(f4v*)(gpart + ((size_t)t * 8 + wv) * 64 + mt * 16 + (l >> 4) * 4) = pv; \
        } \
    } \
    __builtin_amdgcn_sched_barrier(0); \
}

__global__ __launch_bounds__(512, 2)
void gru_kernel(const float* __restrict__ x,
                const u16* __restrict__ Wpkh, const u16* __restrict__ Wpk0g,
                const u16* __restrict__ Wpk1g,
                const float* __restrict__ bih0, const float* __restrict__ bhh0,
                const float* __restrict__ bih1, const float* __restrict__ bhh1,
                const float* __restrict__ l2W,
                u16* __restrict__ h0seq, float* __restrict__ gi0,
                float* __restrict__ gi1, int* syncb, float* __restrict__ gpart) {
    __shared__ u16 hstage[2][32][256];          // 32KB f16 h ping-pong (32 batches)
    __shared__ u16 whhlds[2][8][6][512];        // 96KB: kc=6,7 Whh chunks

    const int tid = threadIdx.x;
    const int wv = tid >> 6, l = tid & 63;
    const int bid = blockIdx.x;

    int* progLp = syncb;            // [0..3]
    int* progHp = syncb + 64;
    int* stHp   = syncb + 128;      // [16][16]
    int* stG0   = syncb + 384;      // [16][8]
    int* stG1   = syncb + 512;      // [16][8]
    char* h0c   = (char*)h0seq;

    if (bid >= 4) {
        // ======================= producers (group-batched) =======================
        const bool isF = bid < 12;
        const int pb = isF ? (bid - 4) : (bid - 12);
        const int mt = wv >> 1, gg = wv & 1;    // wave -> (M-tile, NT-half)
        const int KC = isF ? 4 : 8;
        h8v wrp[8][3];
        {
            const u16* base = isF ? Wpk0g : Wpk1g;
            #pragma unroll
            for (int kc = 0; kc < 8; ++kc)
                if (kc < KC) {
                    #pragma unroll
                    for (int j = 0; j < 3; ++j)
                        wrp[kc][j] = *(const h8v*)(base +
                            (((size_t)(pb * KC + kc) * 6) + gg * 3 + j) * 512 + l * 8);
                }
        }
        float biasp[3];
        const float* bi_ = isF ? bih0 : bih1;
        const float* bh_ = isF ? bhh0 : bhh1;
        #pragma unroll
        for (int j = 0; j < 3; ++j) {
            int NT = pb * 6 + gg * 3 + j;
            int gch = NT * 16 + (l & 15);
            biasp[j] = bi_[gch] + (NT < 32 ? bh_[gch] : 0.0f);  // n-gate: bih only
        }
        int* progPair = syncb + (isF ? 0 : 2);  // two consumer halves
        int* mySt   = isF ? stG0 : stG1;
        float* gid  = isF ? gi0 : gi1;

        for (int gr = 0; gr < NGRP; ++gr) {
            // ring-overwrite throttle (both consumer halves), group frequency
            {
                int v = (l < 2) ? AT_LD(progPair + l) : 0x7fffffff;
                while (!__all(v >= 4 * gr - SLACK)) {
                    __builtin_amdgcn_s_sleep(4);
                    v = (l < 2) ? AT_LD(progPair + l) : 0x7fffffff;
                }
            }
            if (!isF) {
                // h0 group availability
                int sv = (l < 16) ? AT_LD(stHp + (gr & 15) * 16 + l) : 0x7fffffff;
                while (!__all(sv >= gr)) {
                    __builtin_amdgcn_s_sleep(1);
                    sv = (l < 16) ? AT_LD(stHp + (gr & 15) * 16 + l) : 0x7fffffff;
                }
            }
            asm volatile("" ::: "memory");
            if (isF) {
                #pragma unroll 1
                for (int p = 0; p < 2; ++p) {
                    #pragma unroll
                    for (int jj = 0; jj < 2; ++jj) {
                        const int t = gr * 4 + p * 2 + jj;
                        const int s = t & (RSLOT - 1);
                        h8v A[8];
                        const float* xp = x + ((size_t)(mt * 16 + (l & 15)) * NNODE + t) * DCIN
                                            + (l >> 4) * 8;
                        #pragma unroll
                        for (int kc = 0; kc < 4; ++kc) {
                            f4v lo = *(const f4v*)(xp + kc * 32);
                            f4v hi = *(const f4v*)(xp + kc * 32 + 4);
                            h8v a;
                            #pragma unroll
                            for (int e = 0; e < 4; ++e) {
                                a[e] = (_Float16)lo[e]; a[4 + e] = (_Float16)hi[e];
                            }
                            A[kc] = a;
                        }
                        #pragma unroll
                        for (int j = 0; j < 3; ++j) {
                            f4v acc = {biasp[j], biasp[j], biasp[j], biasp[j]};
                            #pragma unroll
                            for (int kc = 0; kc < 4; ++kc)
                                acc = mfma16h(A[kc], wrp[kc][j], acc);
                            int NT = pb * 6 + gg * 3 + j;
                            st_ring_f4((u64*)((char*)gid +
                                (((size_t)s * 48 + NT) * 4 + mt) * 1024 + l * 16), acc);
                        }
                    }
                }
            } else {
                // pipelined 4-step group: prefetch k+1 loads before k's MFMAs
                h8v A0[8], A1[8];
                {
                    const int s0 = (gr * 4) & (RSLOT - 1);
                    #pragma unroll
                    for (int kc = 0; kc < 8; ++kc)
                        A0[kc] = ld_ring_h8((const u64*)(h0c +
                            (((size_t)(s0 * 8 + kc) * 4 + mt) * 64 + l) * 16));
                }
                HSTEP(0, A0, A1, true)
                HSTEP(1, A1, A0, true)
                HSTEP(2, A0, A1, true)
                HSTEP(3, A1, A0, false)
            }
            if (!isF && l == 0) AT_ST(progHp + pb * 8 + wv, gr);  // consumed h0 group
            asm volatile("s_waitcnt vmcnt(0)" ::: "memory");
            __syncthreads();
            if (tid == 0) AT_ST(mySt + (gr & 15) * 8 + pb, gr);   // group complete
        }
        return;
    }

    // ========================= L-blocks (recurrent) =========================
    const bool isL1 = (bid >= 2);
    const int half = bid & 1;                    // batch half: mt = half*2 + mtg
    h8v wr[6][6];                                // Whh kc 0..5 in VGPR/AGPR (144)
    #pragma unroll
    for (int kc = 0; kc < 6; ++kc)
        #pragma unroll
        for (int nt = 0; nt < 6; ++nt)
            wr[kc][nt] = *(const h8v*)(Wpkh +
                ((((size_t)(isL1 ? 8 : 0) + wv) * 8 + kc) * 6 + nt) * 512 + l * 8);
    // kc = 6,7 chunks -> LDS (per-wave slices)
    #pragma unroll
    for (int kcx = 0; kcx < 2; ++kcx)
        #pragma unroll
        for (int nt = 0; nt < 6; ++nt)
            *(h8v*)&whhlds[kcx][wv][nt][l * 8] = *(const h8v*)(Wpkh +
                ((((size_t)(isL1 ? 8 : 0) + wv) * 8 + 6 + kcx) * 6 + nt) * 512 + l * 8);
    const float* bhh_ = isL1 ? bhh1 : bhh0;
    float bhn[2], l2v[2];
    #pragma unroll
    for (int h = 0; h < 2; ++h) {
        int ch = wv * 32 + h * 16 + (l & 15);
        bhn[h] = bhh_[512 + ch];
        l2v[h] = isL1 ? l2W[ch] : 0.0f;
    }
    const char* gis = (const char*)(isL1 ? gi1 : gi0);
    int* stG = isL1 ? stG1 : stG0;
    char* hst = (char*)&hstage[0][0][0];
    f4v gA[6], gB[6];
    bool pfOK = false;
    __syncthreads();

    for (int t = 0; t < NNODE; ++t) {
        const int s = t & (RSLOT - 1);
        const int g = t >> 2, gph = t & 3;
        const int rb = t & 1, wb = rb ^ 1;
        // speculative next-group stamp read (evaluated under mtg0's MFMAs)
        int stvn = 0x7fffffff;
        if (gph == 3 && t + 1 < NNODE && l < 8)
            stvn = AT_LD(stG + ((g + 1) & 15) * 8 + l);
        if (gph == 0) {
            if (!isL1) {
                // h0seq ring overwrite: helpers must have consumed group g-16
                int ph = AT_LD(progHp + l);
                while (!__all(ph >= g - 15)) {
                    __builtin_amdgcn_s_sleep(1);
                    ph = AT_LD(progHp + l);
                }
            }
            if (!pfOK) {
                // blocking fallback: poll group stamp, then load this step's GI
                int sv = (l < 8) ? AT_LD(stG + (g & 15) * 8 + l) : 0x7fffffff;
                while (!__all(sv >= g)) {
                    __builtin_amdgcn_s_sleep(1);
                    sv = (l < 8) ? AT_LD(stG + (g & 15) * 8 + l) : 0x7fffffff;
                }
                asm volatile("" ::: "memory");
                #pragma unroll
                for (int j = 0; j < 6; ++j) {
                    int NT = (j >> 1) * 16 + 2 * wv + (j & 1);
                    gA[j] = ld_ring_f4((const u64*)(gis +
                        (((size_t)s * 48 + NT) * 4 + half * 2) * 1024 + l * 16));
                    gB[j] = ld_ring_f4((const u64*)(gis +
                        (((size_t)s * 48 + NT) * 4 + half * 2 + 1) * 1024 + l * 16));
                }
            }
        }
        bool pfNext = false;
        L_MTG(0, gA)
        L_MTG(1, gB)
        pfOK = pfNext;
        if (wv == 0 && l == 0) AT_ST(progLp + bid, t);
        if (!isL1 && gph == 3) {
            // drain this group's h0 publishes, then per-wave group stamp
            asm volatile("s_waitcnt vmcnt(0)" ::: "memory");
            if (l == 0) AT_ST(stHp + (g & 15) * 16 + half * 8 + wv, g);
        }
        __syncthreads();    // h(t) complete in hstage[wb] for all waves
    }
}

// ------------------------------- final head --------------------------------
__global__ __launch_bounds__(256)
void head_kernel(const float* __restrict__ gpartg, const float* __restrict__ hdot,
                 const float* __restrict__ l1b, const float* __restrict__ l2b,
                 const float* __restrict__ l3W, const float* __restrict__ l3b,
                 float* __restrict__ out) {
    int idx = blockIdx.x * 256 + threadIdx.x;
    if (idx >= NBATCH * NNODE * 12) return;
    int r = idx / 12, oc = idx - r * 12;
    int b = r >> 9, n = r & 511;
    float g = 0.0f;
    #pragma unroll
    for (int k = 0; k < 8; ++k) g += gpartg[((size_t)n * 8 + k) * 64 + b];
    g += l2b[0];
    float hh = hdot[r] + l1b[0];
    out[idx] = g * l3W[oc] + hh * l3W[12 + oc] + l3b[oc];
}

// ---------------------- static side stream (for capture fork) --------------
static hipStream_t g_side = nullptr;
static hipEvent_t  g_evA  = nullptr;
static hipEvent_t  g_evB  = nullptr;
namespace {
struct SideInit {
    SideInit() {
        if (hipStreamCreateWithFlags(&g_side, hipStreamNonBlocking) != hipSuccess) g_side = nullptr;
        if (hipEventCreateWithFlags(&g_evA, hipEventDisableTiming) != hipSuccess) g_evA = nullptr;
        if (hipEventCreateWithFlags(&g_evB, hipEventDisableTiming) != hipSuccess) g_evB = nullptr;
    }
};
static SideInit g_side_init;
}

// ------------------------------ host launcher ------------------------------
extern "C" void kernel_launch(void* const* d_in, const int* in_sizes, int n_in,
                              void* d_out, int out_size, void* d_ws, size_t ws_size,
                              hipStream_t stream) {
    const float* x    = (const float*)d_in[0];
    const int*   ei   = (const int*)  d_in[1];
    const float* ew   = (const float*)d_in[2];
    const float* Wz   = (const float*)d_in[3];
    const float* bz   = (const float*)d_in[4];
    const float* lzW  = (const float*)d_in[5];
    const float* lzb  = (const float*)d_in[6];
    // d_in[7..10] (TGCN r-gate) unused: H0 == 0
    const float* Wh   = (const float*)d_in[11];
    const float* bh   = (const float*)d_in[12];
    const float* lhW  = (const float*)d_in[13];
    const float* lhb  = (const float*)d_in[14];
    const float* Wih0 = (const float*)d_in[15];
    const float* Whh0 = (const float*)d_in[16];
    const float* bih0 = (const float*)d_in[17];
    const float* bhh0 = (const float*)d_in[18];
    const float* Wih1 = (const float*)d_in[19];
    const float* Whh1 = (const float*)d_in[20];
    const float* bih1 = (const float*)d_in[21];
    const float* bhh1 = (const float*)d_in[22];
    const float* l1W  = (const float*)d_in[23];
    const float* l1b  = (const float*)d_in[24];
    const float* l2W  = (const float*)d_in[25];
    const float* l2b  = (const float*)d_in[26];
    const float* l3W  = (const float*)d_in[27];
    const float* l3b  = (const float*)d_in[28];

    char* ws = (char*)d_ws;
    size_t o = 0;
    auto take = [&](size_t nbytes) {
        char* p = ws + o;
        o = (o + nbytes + 255) & ~(size_t)255;
        return p;
    };
    float* deg    = (float*)take(NNODE * 4);
    float* dinv   = (float*)take(NNODE * 4);
    int*   rowptr = (int*)  take((NNODE + 1) * 4);
    int*   cursor = (int*)  take(NNODE * 4);
    int*   col    = (int*)  take((NEDGE + NNODE) * 4);
    float* val    = (float*)take((NEDGE + NNODE) * 4);
    u16*   Wf     = (u16*)  take((size_t)512 * DCIN * 2);
    float* bfold  = (float*)take(512 * 4);
    float* hdot   = (float*)take((size_t)NBATCH * NNODE * 4);
    float* gpart  = (float*)take((size_t)NNODE * 8 * 64 * 4);            // 1 MB
    u16*   Wpkh   = (u16*)  take((size_t)2 * 8 * 8 * 6 * 64 * 8 * 2);    // 786 KB
    u16*   Wpk0g  = (u16*)  take((size_t)8 * 4 * 6 * 64 * 8 * 2);        // 196 KB
    u16*   Wpk1g  = (u16*)  take((size_t)8 * 8 * 6 * 64 * 8 * 2);        // 393 KB
    u16*   h0seq  = (u16*)  take((size_t)RSLOT * 8 * 4 * 64 * 8 * 2);    // 2 MB
    float* gi0    = (float*)take((size_t)RSLOT * 48 * 4 * 64 * 4 * 4);   // 12.6 MB
    float* gi1    = (float*)take((size_t)RSLOT * 48 * 4 * 64 * 4 * 4);   // 12.6 MB
    int*   syncb  = (int*)  take(16384);
    if (o > ws_size) return;   // clean-failure signature: absmax == 4.57e-2

    const bool fork = (g_side && g_evA && g_evB);
    hipStream_t sideS = fork ? g_side : stream;

    // main: init (deg/counts + stamps/progress to -1)
    init_kernel<<<16, 256, 0, stream>>>(deg, cursor, syncb);

    if (fork) {
        hipEventRecord(g_evA, stream);
        hipStreamWaitEvent(sideS, g_evA, 0);
    }

    // side branch: graph preprocessing -> fold -> TGCN (independent of GRU)
    edge_deg_kernel<<<NEDGE / 256, 256, 0, sideS>>>(ei, ew, deg, cursor);
    scan_kernel<<<1, NNODE, 0, sideS>>>(deg, cursor, dinv, rowptr, cursor, col, val);
    fill_kernel<<<NEDGE / 256, 256, 0, sideS>>>(ei, ew, dinv, cursor, col, val);
    fold_kernel<<<512, DCIN, 0, sideS>>>(Wz, lzW, bz, lzb, Wh, lhW, bh, lhb, Wf, bfold);
    tgcn_kernel<<<512, 256, 0, sideS>>>(x, rowptr, col, val, Wf, bfold, l1W, hdot);
    if (fork) hipEventRecord(g_evB, sideS);

    // main branch: weight repacks -> persistent GRU pipeline
    pack_whh_kernel<<<(2 * 8 * 8 * 6 * 64 + 255) / 256, 256, 0, stream>>>(Whh0, Whh1, Wpkh);
    pack_wih_kernel<<<(8 * 4 * 6 * 64 + 255) / 256, 256, 0, stream>>>(Wih0, DCIN, 4, Wpk0g);
    pack_wih_kernel<<<(8 * 8 * 6 * 64 + 255) / 256, 256, 0, stream>>>(Wih1, DHID, 8, Wpk1g);
    gru_kernel<<<20, 512, 0, stream>>>(x, Wpkh, Wpk0g, Wpk1g, bih0, bhh0,
                                       bih1, bhh1, l2W, h0seq, gi0, gi1,
                                       syncb, gpart);

    // join + head
    if (fork) hipStreamWaitEvent(stream, g_evB, 0);
    head_kernel<<<(NBATCH * NNODE * 12 + 255) / 256, 256, 0, stream>>>(
        gpart, hdot, l1b, l2b, l3W, l3b, (float*)d_out);
    (void)in_sizes; (void)n_in; (void)out_size;
}

// Round 8
// 2287.087 us; speedup vs baseline: 2.6375x; 2.6375x over previous
//
#include <hip/hip_runtime.h>

// ---------------------------------------------------------------------------
// TGCN2 forward, MI355X gfx950. All float tensors fp32; edge_index i32.
// Math: H0=0 => TGCN R-gate dead, Hn=(1-Z)*H~, concat([c,0])@L == c@L_top;
// A(xW)L == (Ax)(WL) -> folded TGCN gate weights; head dots fused.
// GRU: 32-block spatial pipeline (16 blocks/layer x 16 channels), LDS-resident
// weight slices, agent-scope fragment rings. R10: per-WAVE stamps co-located
// with ring slots (drain -> stamp store, no barrier/leader on the visibility
// path; per-step barrier KEPT after publish for skew reset — R6 showed
// removing it regresses), and L1 consumes h0 BEFORE its h1 self-loop wait.
// R9: phase-split (x-part pre-wait) + in-kernel x conversion. TGCN branch on
// a second captured stream (R7).
// R18 NOTE: this is the R0/R10 kernel RESTORED VERBATIM. Rounds 11-17
// explored (a) deeper prefetch on this design, (b) sentinel payload-polling,
// (c) an intra-block-recurrence redesign with streamed GI + group-batched
// sync + register pipelining. All measured WORSE (2284/3770/6032/9484/12960
// vs 2274 here). The 4.1us/step floor of this design = one all-to-all
// cross-XCD LLC round trip per recurrence step + compute + barrier; two
// independent sync mechanisms (flags here, payload sentinels in R12) both
// land on it, so it is structural, not sync-mechanics.
// ---------------------------------------------------------------------------

typedef unsigned short u16;
typedef unsigned long long u64;
typedef short s8v __attribute__((ext_vector_type(8)));
typedef float f4v __attribute__((ext_vector_type(4)));

#define NBATCH 64
#define NNODE  512
#define DCIN   128
#define DHID   256
#define NEDGE  8192
#define RING   8
#define SLOTU16 16384   // 32KB per ring slot: 4 Mt x 8 kc x 1KB fragments

__device__ __forceinline__ u16 f2b(float f) {
    union { float f; unsigned int i; } v; v.f = f;
    unsigned int x = v.i;
    return (u16)((x + 0x7FFFu + ((x >> 16) & 1u)) >> 16);   // RNE
}
__device__ __forceinline__ float sigm(float x)  { return 1.0f / (1.0f + __expf(-x)); }
__device__ __forceinline__ float tanh_(float x) { return 1.0f - 2.0f / (1.0f + __expf(2.0f * x)); }
__device__ __forceinline__ f4v mfma16(s8v a, s8v b, f4v c) {
    return __builtin_amdgcn_mfma_f32_16x16x32_bf16(a, b, c, 0, 0, 0);
}
__device__ __forceinline__ s8v ld_ring(const u64* p) {
    union { u64 d[2]; s8v v; } u;
    u.d[0] = __hip_atomic_load(p,     __ATOMIC_RELAXED, __HIP_MEMORY_SCOPE_AGENT);
    u.d[1] = __hip_atomic_load(p + 1, __ATOMIC_RELAXED, __HIP_MEMORY_SCOPE_AGENT);
    return u.v;
}
__device__ __forceinline__ void st_ring(u64* p, s8v v) {
    union { s8v v; u64 d[2]; } u; u.v = v;
    __hip_atomic_store(p,     u.d[0], __ATOMIC_RELAXED, __HIP_MEMORY_SCOPE_AGENT);
    __hip_atomic_store(p + 1, u.d[1], __ATOMIC_RELAXED, __HIP_MEMORY_SCOPE_AGENT);
}
// lanes 0..15 poll 16 per-wave stamps (one 64B line)
__device__ __forceinline__ void wait_stamp(const int* sp, int tgt, int l) {
    while (true) {
        int v = 0x7fffffff;
        if (l < 16) v = __hip_atomic_load(sp + l, __ATOMIC_RELAXED, __HIP_MEMORY_SCOPE_AGENT);
        if (__all(v >= tgt)) break;
        __builtin_amdgcn_s_sleep(2);
    }
    asm volatile("" ::: "memory");
}
// stamps on lanes 0..15, block-flag slack on lanes 16..31
__device__ __forceinline__ void wait_stamp_slack(const int* sp, int tgt,
                                                 const int* fp, int tgtf, int l) {
    while (true) {
        int v = 0x7fffffff, tg = -0x7fffffff;
        if (l < 16)      { v = __hip_atomic_load(sp + l, __ATOMIC_RELAXED, __HIP_MEMORY_SCOPE_AGENT); tg = tgt; }
        else if (l < 32) { v = __hip_atomic_load(fp + (l - 16), __ATOMIC_RELAXED, __HIP_MEMORY_SCOPE_AGENT); tg = tgtf; }
        if (__all(v >= tg)) break;
        __builtin_amdgcn_s_sleep(2);
    }
    asm volatile("" ::: "memory");
}
// 8 consecutive fp32 -> bf16 fragment chunk (bit-identical to repack path)
__device__ __forceinline__ s8v cvt8(const float* p) {
    s8v r;
    #pragma unroll
    for (int e = 0; e < 8; ++e) r[e] = (short)f2b(p[e]);
    return r;
}

// --------------------------- graph preprocessing ---------------------------
__global__ void init_kernel(float* deg, int* counts, int* syncb) {
    int i = blockIdx.x * blockDim.x + threadIdx.x;
    if (i < NNODE) { deg[i] = 2.0f; counts[i] = 1; }
    if (i < 2048) syncb[i] = 0;   // flags + per-wave stamps
}

__global__ void edge_deg_kernel(const int* __restrict__ ei, const float* __restrict__ ew,
                                float* deg, int* counts) {
    int e = blockIdx.x * blockDim.x + threadIdx.x;
    if (e < NEDGE) {
        int t = ei[NEDGE + e];
        atomicAdd(&deg[t], ew[e]);
        atomicAdd(&counts[t], 1);
    }
}

__global__ void scan_kernel(const float* __restrict__ deg, const int* __restrict__ counts,
                            float* __restrict__ dinv, int* __restrict__ rowptr,
                            int* __restrict__ cursor, int* __restrict__ col,
                            float* __restrict__ val) {
    __shared__ int sc[NNODE];
    int i = threadIdx.x;
    float d = deg[i];
    float di = (d > 0.0f) ? (1.0f / sqrtf(d)) : 0.0f;
    dinv[i] = di;
    int cnt = counts[i];
    sc[i] = cnt;
    __syncthreads();
    for (int ofs = 1; ofs < NNODE; ofs <<= 1) {
        int add = (i >= ofs) ? sc[i - ofs] : 0;
        __syncthreads();
        sc[i] += add;
        __syncthreads();
    }
    int ex = sc[i] - cnt;
    rowptr[i] = ex;
    if (i == NNODE - 1) rowptr[NNODE] = sc[NNODE - 1];
    col[ex] = i;
    val[ex] = di * 2.0f * di;
    cursor[i] = ex + 1;
}

__global__ void fill_kernel(const int* __restrict__ ei, const float* __restrict__ ew,
                            const float* __restrict__ dinv, int* cursor,
                            int* __restrict__ col, float* __restrict__ val) {
    int e = blockIdx.x * blockDim.x + threadIdx.x;
    if (e < NEDGE) {
        int s = ei[e], t = ei[NEDGE + e];
        int p = atomicAdd(&cursor[t], 1);
        col[p] = s;
        val[p] = dinv[s] * ew[e] * dinv[t];
    }
}

// Wf[2j+g][k] = sum_m Wg[k][m]*Lg_top[m][j]; bfold[2j+g] = bg@Lg_top[:,j]+lgb[j]
__global__ void fold_kernel(const float* __restrict__ Wz, const float* __restrict__ lzW,
                            const float* __restrict__ bz, const float* __restrict__ lzb,
                            const float* __restrict__ Wh, const float* __restrict__ lhW,
                            const float* __restrict__ bh, const float* __restrict__ lhb,
                            u16* __restrict__ Wf, float* __restrict__ bfold) {
    int nidx = blockIdx.x;
    int g = nidx & 1, j = nidx >> 1;
    int k = threadIdx.x;
    const float* W = g ? Wh : Wz;
    const float* L = g ? lhW : lzW;
    float acc = 0.0f;
    for (int m = 0; m < DHID; ++m)
        acc += W[k * DHID + m] * L[m * DHID + j];
    Wf[nidx * DCIN + k] = f2b(acc);
    if (k == 0) {
        const float* bg = g ? bh : bz;
        const float* lb = g ? lhb : lzb;
        float ab = 0.0f;
        for (int m = 0; m < DHID; ++m) ab += bg[m] * L[m * DHID + j];
        bfold[nidx] = ab + lb[j];
    }
}

// ----------------------------- weight repack -------------------------------
__global__ void repack_w_kernel(const float* __restrict__ Wih, const float* __restrict__ Whh,
                                int KCX, int KC, int KX, int KH, u16* __restrict__ dst) {
    int id = blockIdx.x * 256 + threadIdx.x;
    int total = 16 * KC * 3 * 64;
    if (id >= total) return;
    int l = id & 63; int rest = id >> 6;
    int g = rest % 3; rest /= 3;
    int kc = rest % KC; rest /= KC;
    int r = rest;
    int j = r * 16 + (l & 15);
    int q = l >> 4;
    const float* src; int k;
    if (kc < KCX) { src = Wih + (size_t)(g * 256 + j) * KX; k = kc * 32 + q * 8; }
    else          { src = Whh + (size_t)(g * 256 + j) * KH; k = (kc - KCX) * 32 + q * 8; }
    u16* d = dst + (((size_t)(r * KC + kc)) * 3 + g) * 512 + l * 8;
    #pragma unroll
    for (int e = 0; e < 8; ++e) d[e] = f2b(src[k + e]);
}

// --------------- fused TGCN: aggregate + GEMM + cell + l1-dot --------------
__global__ __launch_bounds__(256)
void tgcn_kernel(const float* __restrict__ x, const int* __restrict__ rowptr,
                 const int* __restrict__ col, const float* __restrict__ val,
                 const u16* __restrict__ Wf, const float* __restrict__ bfold,
                 const float* __restrict__ l1W, float* __restrict__ hdot) {
    __shared__ u16 As[64][136];
    const int tid = threadIdx.x;
    const int bx = blockIdx.x;
    const int b = bx >> 3;
    const int n0 = (bx & 7) * 64;
    {
        const int c = tid & 127;
        const int half = tid >> 7;
        for (int it = 0; it < 32; ++it) {
            int r = it * 2 + half;
            int n = n0 + r;
            int s = rowptr[n], e = rowptr[n + 1];
            float acc = 0.0f;
            for (int i = s; i < e; ++i)
                acc += val[i] * x[((size_t)b * NNODE + col[i]) * DCIN + c];
            As[r][c] = f2b(acc);
        }
    }
    __syncthreads();
    const int w = tid >> 6, l = tid & 63;
    const int ncol = l & 15, q = l >> 4, ko = q * 8;
    s8v af[4];
    #pragma unroll
    for (int kc = 0; kc < 4; ++kc)
        af[kc] = *(const s8v*)(&As[w * 16 + ncol][kc * 32 + ko]);
    float partial[4] = {0.f, 0.f, 0.f, 0.f};
    for (int nc = 0; nc < 32; ++nc) {
        int n = nc * 16 + ncol;
        const u16* brow = Wf + (size_t)n * DCIN + ko;
        f4v acc = {0.f, 0.f, 0.f, 0.f};
        #pragma unroll
        for (int kc = 0; kc < 4; ++kc)
            acc = mfma16(af[kc], *(const s8v*)(brow + kc * 32), acc);
        float bias = bfold[n];
        float l1w = l1W[n >> 1];
        #pragma unroll
        for (int rr = 0; rr < 4; ++rr) {
            float v = acc[rr] + bias;
            float o = __shfl_xor(v, 1);
            float zpre = (ncol & 1) ? o : v;
            float hpre = (ncol & 1) ? v : o;
            float hn = (1.0f - sigm(zpre)) * tanh_(hpre);
            hn = hn > 0.0f ? hn : 0.0f;
            if (!(ncol & 1)) partial[rr] += hn * l1w;
        }
    }
    #pragma unroll
    for (int rr = 0; rr < 4; ++rr) {
        float p = partial[rr];
        p += __shfl_xor(p, 1); p += __shfl_xor(p, 2);
        p += __shfl_xor(p, 4); p += __shfl_xor(p, 8);
        if (ncol == 0)
            hdot[bx * 64 + w * 16 + q * 4 + rr] = p;
    }
}

// ------ GRU: 32-block pipeline, per-wave stamps + reordered L1 (R10) -------
// syncb: [0..15]=fL0 block flags, [16..31]=fL1, [64..575]=st0[slot][w][blk],
// [576..1087]=st1. stamp value = producer step + 1.
__global__ __launch_bounds__(256)
void gru_pipe_kernel(const float* __restrict__ x,
                     const u16* __restrict__ Wpk0, const u16* __restrict__ Wpk1,
                     const float* __restrict__ bih0, const float* __restrict__ bhh0,
                     const float* __restrict__ bih1, const float* __restrict__ bhh1,
                     const float* __restrict__ l2W,
                     u16* __restrict__ h0ring, u16* __restrict__ h1ring,
                     int* syncb, float* __restrict__ gpartg) {
    __shared__ u16 wlds[16 * 3 * 512];          // 48KB max (L1); L0 uses 36KB
    __shared__ u16 tile[4][16][16];             // per-wave epilogue staging

    const int tid = threadIdx.x;
    const int w = tid >> 6;                     // wave = M-tile (16 batches)
    const int l = tid & 63;
    const int q = l >> 4, ncol = l & 15;
    const bool isL1 = blockIdx.x >= 16;
    const int rblk = blockIdx.x & 15;           // 16-channel output slice
    const int KC = isL1 ? 16 : 12;

    int* fL1 = syncb + 16;
    int* st0 = syncb + 64;
    int* st1 = syncb + 64 + 512;

    // ---- load weight slice into LDS (once) ----
    {
        const s8v* src = (const s8v*)((isL1 ? Wpk1 : Wpk0) + (size_t)rblk * KC * 3 * 512);
        s8v* dst = (s8v*)wlds;
        for (int i = tid; i < KC * 3 * 64; i += 256) dst[i] = src[i];
    }
    // ---- per-lane constants ----
    const int j = rblk * 16 + ncol;
    const float* bihp = isL1 ? bih1 : bih0;
    const float* bhhp = isL1 ? bhh1 : bhh0;
    const float br = bihp[j] + bhhp[j];
    const float bz = bihp[256 + j] + bhhp[256 + j];
    const float bi = bihp[512 + j];
    const float bhn = bhhp[512 + j];
    const float l2v = isL1 ? l2W[j] : 0.0f;
    float hreg[4] = {0.f, 0.f, 0.f, 0.f};
    const int qbase = 2 * (rblk & 1);           // publish q-half for this slice
    u16* myring = isL1 ? h1ring : h0ring;
    int* myst = isL1 ? st1 : st0;
    int* myflag = (isL1 ? fL1 : syncb) + rblk;
    const s8v* wf = (const s8v*)wlds;
    // L0's x A-fragment source: batch b = w*16+ncol, col base q*8
    const float* xrow = x + ((size_t)(w * 16 + ncol) * NNODE) * DCIN + q * 8;
    __syncthreads();

    for (int t = 0; t < NNODE; ++t) {
        const int scur = t & (RING - 1), sprev = (t - 1) & (RING - 1);
        f4v accR = {0,0,0,0}, accZ = {0,0,0,0}, accNi = {0,0,0,0}, accNh = {0,0,0,0};
        if (!isL1) {
            // phase A: x-part — no dependency, runs before any wait
            const float* xp = xrow + (size_t)t * DCIN;
            #pragma unroll
            for (int kc = 0; kc < 4; ++kc) {
                s8v a = cvt8(xp + kc * 32);
                accR  = mfma16(a, wf[(kc * 3 + 0) * 64 + l], accR);
                accZ  = mfma16(a, wf[(kc * 3 + 1) * 64 + l], accZ);
                accNi = mfma16(a, wf[(kc * 3 + 2) * 64 + l], accNi);
            }
            // phase B: wait per-wave h0(t-1) stamps (+ ring slack), then h-part
            if (t > 0) {
                wait_stamp_slack(st0 + sprev * 64 + w * 16, t, fL1, t - 7, l);
                const u64* s1 = (const u64*)(h0ring + (size_t)sprev * SLOTU16);
                s8v a1[8];
                #pragma unroll
                for (int k = 0; k < 8; ++k)
                    a1[k] = ld_ring(s1 + (size_t)(w * 8 + k) * 128 + l * 2);
                #pragma unroll
                for (int k = 0; k < 8; ++k) {
                    int kc = 4 + k;
                    accR  = mfma16(a1[k], wf[(kc * 3 + 0) * 64 + l], accR);
                    accZ  = mfma16(a1[k], wf[(kc * 3 + 1) * 64 + l], accZ);
                    accNh = mfma16(a1[k], wf[(kc * 3 + 2) * 64 + l], accNh);
                }
            }
        } else {
            // phase A: h0(t) — L0 runs ahead, wait nearly free; do it FIRST so
            // the h1 self-loop (phase B) excludes this load round trip.
            wait_stamp(st0 + scur * 64 + w * 16, t + 1, l);
            const u64* s0 = (const u64*)(h0ring + (size_t)scur * SLOTU16);
            s8v a0[8];
            #pragma unroll
            for (int k = 0; k < 8; ++k)
                a0[k] = ld_ring(s0 + (size_t)(w * 8 + k) * 128 + l * 2);
            #pragma unroll
            for (int k = 0; k < 8; ++k) {
                accR  = mfma16(a0[k], wf[(k * 3 + 0) * 64 + l], accR);
                accZ  = mfma16(a0[k], wf[(k * 3 + 1) * 64 + l], accZ);
                accNi = mfma16(a0[k], wf[(k * 3 + 2) * 64 + l], accNi);
            }
            // phase B: own h1(t-1) self-loop (binding wait, propagation
            // overlapped with phase A)
            if (t > 0) {
                wait_stamp(st1 + sprev * 64 + w * 16, t, l);
                const u64* s1 = (const u64*)(h1ring + (size_t)sprev * SLOTU16);
                s8v a1[8];
                #pragma unroll
                for (int k = 0; k < 8; ++k)
                    a1[k] = ld_ring(s1 + (size_t)(w * 8 + k) * 128 + l * 2);
                #pragma unroll
                for (int k = 0; k < 8; ++k) {
                    int kc = 8 + k;
                    accR  = mfma16(a1[k], wf[(kc * 3 + 0) * 64 + l], accR);
                    accZ  = mfma16(a1[k], wf[(kc * 3 + 1) * 64 + l], accZ);
                    accNh = mfma16(a1[k], wf[(kc * 3 + 2) * 64 + l], accNh);
                }
            }
        }
        // ---- gate epilogue (all gates in-wave; fp32 h in registers) ----
        float pd[4];
        #pragma unroll
        for (int rr = 0; rr < 4; ++rr) {
            float rv = sigm(accR[rr] + br);
            float zv = sigm(accZ[rr] + bz);
            float nv = tanh_(accNi[rr] + bi + rv * (accNh[rr] + bhn));
            float hn = nv + zv * (hreg[rr] - nv);
            hreg[rr] = hn;
            tile[w][q * 4 + rr][ncol] = f2b(hn);
            pd[rr] = hn * l2v;
        }
        // ---- publish fragment, drain, per-wave stamp (critical path) ----
        if (q == qbase || q == qbase + 1) {
            s8v v = *(const s8v*)&tile[w][ncol][8 * (q - qbase)];
            u64* dst = (u64*)(myring + (size_t)scur * SLOTU16)
                       + (size_t)(w * 8 + (rblk >> 1)) * 128 + l * 2;
            st_ring(dst, v);
        }
        asm volatile("s_waitcnt vmcnt(0)" ::: "memory");
        if (l == 0)
            __hip_atomic_store(myst + scur * 64 + w * 16 + rblk, t + 1,
                               __ATOMIC_RELAXED, __HIP_MEMORY_SCOPE_AGENT);
        // ---- off-critical-path: l2-dot partials ----
        if (isL1) {
            #pragma unroll
            for (int rr = 0; rr < 4; ++rr) {
                float v = pd[rr];
                v += __shfl_xor(v, 1); v += __shfl_xor(v, 2);
                v += __shfl_xor(v, 4); v += __shfl_xor(v, 8);
                if (ncol == 0)
                    gpartg[((size_t)t * 16 + rblk) * 64 + w * 16 + q * 4 + rr] = v;
            }
        }
        __syncthreads();   // per-step skew reset (R6: removing this regressed)
        if (tid == 0)
            __hip_atomic_store(myflag, t + 1,
                               __ATOMIC_RELAXED, __HIP_MEMORY_SCOPE_AGENT);
    }
}

// ------------------------------- final head --------------------------------
__global__ __launch_bounds__(256)
void head_kernel(const float* __restrict__ gpartg, const float* __restrict__ hdot,
                 const float* __restrict__ l1b, const float* __restrict__ l2b,
                 const float* __restrict__ l3W, const float* __restrict__ l3b,
                 float* __restrict__ out) {
    int idx = blockIdx.x * 256 + threadIdx.x;
    if (idx >= NBATCH * NNODE * 12) return;
    int r = idx / 12, oc = idx - r * 12;
    int b = r >> 9, n = r & 511;
    float g = 0.0f;
    #pragma unroll
    for (int k = 0; k < 16; ++k) g += gpartg[((size_t)n * 16 + k) * 64 + b];
    g += l2b[0];
    float hh = hdot[r] + l1b[0];
    out[idx] = g * l3W[oc] + hh * l3W[12 + oc] + l3b[oc];
}

// ---------------------- static side stream (for capture fork) --------------
static hipStream_t g_side = nullptr;
static hipEvent_t  g_evA  = nullptr;
static hipEvent_t  g_evB  = nullptr;
namespace {
struct SideInit {
    SideInit() {
        if (hipStreamCreateWithFlags(&g_side, hipStreamNonBlocking) != hipSuccess) g_side = nullptr;
        if (hipEventCreateWithFlags(&g_evA, hipEventDisableTiming) != hipSuccess) g_evA = nullptr;
        if (hipEventCreateWithFlags(&g_evB, hipEventDisableTiming) != hipSuccess) g_evB = nullptr;
    }
};
static SideInit g_side_init;
}

// ------------------------------ host launcher ------------------------------
extern "C" void kernel_launch(void* const* d_in, const int* in_sizes, int n_in,
                              void* d_out, int out_size, void* d_ws, size_t ws_size,
                              hipStream_t stream) {
    const float* x    = (const float*)d_in[0];
    const int*   ei   = (const int*)  d_in[1];
    const float* ew   = (const float*)d_in[2];
    const float* Wz   = (const float*)d_in[3];
    const float* bz   = (const float*)d_in[4];
    const float* lzW  = (const float*)d_in[5];
    const float* lzb  = (const float*)d_in[6];
    // d_in[7..10] (TGCN r-gate) unused: H0 == 0
    const float* Wh   = (const float*)d_in[11];
    const float* bh   = (const float*)d_in[12];
    const float* lhW  = (const float*)d_in[13];
    const float* lhb  = (const float*)d_in[14];
    const float* Wih0 = (const float*)d_in[15];
    const float* Whh0 = (const float*)d_in[16];
    const float* bih0 = (const float*)d_in[17];
    const float* bhh0 = (const float*)d_in[18];
    const float* Wih1 = (const float*)d_in[19];
    const float* Whh1 = (const float*)d_in[20];
    const float* bih1 = (const float*)d_in[21];
    const float* bhh1 = (const float*)d_in[22];
    const float* l1W  = (const float*)d_in[23];
    const float* l1b  = (const float*)d_in[24];
    const float* l2W  = (const float*)d_in[25];
    const float* l2b  = (const float*)d_in[26];
    const float* l3W  = (const float*)d_in[27];
    const float* l3b  = (const float*)d_in[28];

    char* ws = (char*)d_ws;
    size_t o = 0;
    auto take = [&](size_t nbytes) {
        char* p = ws + o;
        o = (o + nbytes + 255) & ~(size_t)255;
        return p;
    };
    float* deg    = (float*)take(NNODE * 4);
    float* dinv   = (float*)take(NNODE * 4);
    int*   rowptr = (int*)  take((NNODE + 1) * 4);
    int*   cursor = (int*)  take(NNODE * 4);
    int*   col    = (int*)  take((NEDGE + NNODE) * 4);
    float* val    = (float*)take((NEDGE + NNODE) * 4);
    u16*   Wf     = (u16*)  take((size_t)512 * DCIN * 2);
    float* bfold  = (float*)take(512 * 4);
    float* hdot   = (float*)take((size_t)NBATCH * NNODE * 4);
    float* gpartg = (float*)take((size_t)NNODE * 16 * 64 * 4);         // 2 MB
    u16*   Wpk0   = (u16*)  take((size_t)16 * 12 * 3 * 512 * 2);       // 590 KB
    u16*   Wpk1   = (u16*)  take((size_t)16 * 16 * 3 * 512 * 2);       // 786 KB
    u16*   h0ring = (u16*)  take((size_t)RING * SLOTU16 * 2);          // 256 KB
    u16*   h1ring = (u16*)  take((size_t)RING * SLOTU16 * 2);          // 256 KB
    int*   syncb  = (int*)  take(8192);                                // flags+stamps
    if (o > ws_size) return;   // clean-failure signature: absmax == 4.57e-2

    const bool fork = (g_side && g_evA && g_evB);
    hipStream_t sideS = fork ? g_side : stream;

    // main: init (zeroes flags + stamps + deg/counts)
    init_kernel<<<8, 256, 0, stream>>>(deg, cursor, syncb);

    if (fork) {
        hipEventRecord(g_evA, stream);
        hipStreamWaitEvent(sideS, g_evA, 0);
    }

    // side branch: graph preprocessing -> fold -> TGCN (independent of GRU)
    edge_deg_kernel<<<NEDGE / 256, 256, 0, sideS>>>(ei, ew, deg, cursor);
    scan_kernel<<<1, NNODE, 0, sideS>>>(deg, cursor, dinv, rowptr, cursor, col, val);
    fill_kernel<<<NEDGE / 256, 256, 0, sideS>>>(ei, ew, dinv, cursor, col, val);
    fold_kernel<<<512, DCIN, 0, sideS>>>(Wz, lzW, bz, lzb, Wh, lhW, bh, lhb, Wf, bfold);
    tgcn_kernel<<<512, 256, 0, sideS>>>(x, rowptr, col, val, Wf, bfold, l1W, hdot);
    if (fork) hipEventRecord(g_evB, sideS);

    // main branch: weight repacks -> GRU pipeline (x converted in-kernel)
    repack_w_kernel<<<(16 * 12 * 3 * 64 + 255) / 256, 256, 0, stream>>>(
        Wih0, Whh0, 4, 12, DCIN, DHID, Wpk0);
    repack_w_kernel<<<(16 * 16 * 3 * 64 + 255) / 256, 256, 0, stream>>>(
        Wih1, Whh1, 8, 16, DHID, DHID, Wpk1);
    gru_pipe_kernel<<<32, 256, 0, stream>>>(x, Wpk0, Wpk1, bih0, bhh0,
                                            bih1, bhh1, l2W, h0ring, h1ring,
                                            syncb, gpartg);

    // join + head
    if (fork) hipStreamWaitEvent(stream, g_evB, 0);
    head_kernel<<<(NBATCH * NNODE * 12 + 255) / 256, 256, 0, stream>>>(
        gpartg, hdot, l1b, l2b, l3W, l3b, (float*)d_out);
    (void)in_sizes; (void)n_in; (void)out_size;
}